// Round 1
// baseline (5699.679 us; speedup 1.0000x reference)
//
#include <hip/hip_runtime.h>
#include <stdint.h>

#define T_LEN 512
#define BATCH 128
#define HID 256
#define MROWS (T_LEN*BATCH)   // 65536
#define KIN 512

typedef __attribute__((ext_vector_type(8))) short short8;
typedef __attribute__((ext_vector_type(4))) float f32x4;
typedef __attribute__((ext_vector_type(4))) unsigned short u16x4;

static __device__ __forceinline__ float bf2f(unsigned short u) {
  union { unsigned int u; float f; } c; c.u = ((unsigned int)u) << 16; return c.f;
}
static __device__ __forceinline__ unsigned short f2bf(float f) {
  union { float f; unsigned int u; } c; c.f = f;
  unsigned int x = c.u;
  x += 0x7fffu + ((x >> 16) & 1u);   // RNE
  return (unsigned short)(x >> 16);
}
static __device__ __forceinline__ void gload_lds16(const void* g, void* l) {
  __builtin_amdgcn_global_load_lds((const __attribute__((address_space(1))) unsigned int*)g,
                                   (__attribute__((address_space(3))) unsigned int*)l,
                                   16, 0, 0);
}
static __device__ __forceinline__ float sigm(float x) { return 1.0f / (1.0f + __expf(-x)); }
static __device__ __forceinline__ float tanh_f(float x) { return 1.0f - 2.0f / (1.0f + __expf(2.0f * x)); }

// ---------------- fp32 -> bf16 conversion (n % 4 == 0) ----------------
__global__ void cvt_bf16(const float* __restrict__ in, unsigned short* __restrict__ out, long n) {
  long i = ((long)blockIdx.x * blockDim.x + threadIdx.x) * 4;
  const long stride = (long)gridDim.x * blockDim.x * 4;
  for (; i < n; i += stride) {
    f32x4 v = *(const f32x4*)(in + i);
    u16x4 o;
    o[0] = f2bf(v[0]); o[1] = f2bf(v[1]); o[2] = f2bf(v[2]); o[3] = f2bf(v[3]);
    *(u16x4*)(out + i) = o;
  }
}

// ---------------- input GEMM: gate_x = A[65536,512] * W[1536,512]^T + bias ----------------
// Output gx layout: [dir][m][768] bf16. b_ih folded for all gates, b_hh folded for r,z only.
__global__ __launch_bounds__(256) void gemm_gx(
    const unsigned short* __restrict__ A,
    const unsigned short* __restrict__ Bw,
    const float* __restrict__ bih,
    const float* __restrict__ bhh,
    unsigned short* __restrict__ gx)
{
  __shared__ unsigned short As[128*64];
  __shared__ unsigned short Bs[128*64];
  const int tid = threadIdx.x, lane = tid & 63, wv = tid >> 6;
  const int bid = blockIdx.x;
  const int nt = bid % 12; const long mt = bid / 12;
  const long m0 = mt * 128; const int n0 = nt * 128;
  const int wm = wv >> 1, wn = wv & 1;
  const int r8 = lane >> 3, c8 = lane & 7;

  f32x4 acc[4][4];
  #pragma unroll
  for (int i = 0; i < 4; ++i) {
    #pragma unroll
    for (int j = 0; j < 4; ++j) acc[i][j] = (f32x4)0.0f;
  }

  for (int kt = 0; kt < 8; ++kt) {
    const int kb = kt * 64;
    #pragma unroll
    for (int c = 0; c < 4; ++c) {
      const int rr = c*32 + wv*8;
      gload_lds16(A  + (m0 + rr + r8) * (long)KIN + kb + c8*8, &As[rr*64]);
      gload_lds16(Bw + (long)(n0 + rr + r8) * KIN + kb + c8*8, &Bs[rr*64]);
    }
    __syncthreads();
    #pragma unroll
    for (int kk = 0; kk < 2; ++kk) {
      short8 af[4], bfr[4];
      #pragma unroll
      for (int i = 0; i < 4; ++i)
        af[i] = *(const short8*)&As[(wm*64 + i*16 + (lane&15))*64 + kk*32 + (lane>>4)*8];
      #pragma unroll
      for (int j = 0; j < 4; ++j)
        bfr[j] = *(const short8*)&Bs[(wn*64 + j*16 + (lane&15))*64 + kk*32 + (lane>>4)*8];
      #pragma unroll
      for (int i = 0; i < 4; ++i) {
        #pragma unroll
        for (int j = 0; j < 4; ++j)
          acc[i][j] = __builtin_amdgcn_mfma_f32_16x16x32_bf16(af[i], bfr[j], acc[i][j], 0, 0, 0);
      }
    }
    __syncthreads();
  }

  const int d = (n0 >= 768) ? 1 : 0;
  #pragma unroll
  for (int j = 0; j < 4; ++j) {
    const int n = n0 + wn*64 + j*16 + (lane & 15);
    const int g = n - d*768;
    const float bias = bih[n] + ((g < 512) ? bhh[n] : 0.0f);
    #pragma unroll
    for (int i = 0; i < 4; ++i) {
      const long row = m0 + wm*64 + i*16 + (lane >> 4)*4;
      unsigned short* op = gx + ((long)d*MROWS + row)*768 + g;
      #pragma unroll
      for (int r = 0; r < 4; ++r)
        op[(long)r*768] = f2bf(acc[i][j][r] + bias);
    }
  }
}

// ---------------- recurrent scan: weight-stationary in registers ----------------
// Grid: 16 WGs (dir = blk>>3, batch slice of 16 = blk&7), 512 threads (8 waves).
// Wave v holds W_hh rows [v*96, v*96+96) as MFMA A-frags (192 VGPRs of bf16).
// h lives in LDS pre-formatted as MFMA B-frags (linear -> conflict-free ds_read_b128).
// gh exchanged via col-major LDS [16][772] (stride 772 verified conflict-free).
__global__ __launch_bounds__(512) void gru_rec(
    const unsigned short* __restrict__ gx,    // [2][65536][768] bf16
    const unsigned short* __restrict__ Whh,   // [2][768][256] bf16 (this layer)
    const float* __restrict__ bhh,            // [2][768] fp32 (this layer)
    const float* __restrict__ h0,             // [6][128][256]
    unsigned short* __restrict__ act,         // [65536][512] bf16 (layer output)
    float* __restrict__ hOut,                 // d_out [6][128][256]
    const int layer)
{
  __shared__ float ghbuf[16*772];
  __shared__ unsigned short hT2[4096];
  const int tid = threadIdx.x, lane = tid & 63, wv = tid >> 6;
  const int d = blockIdx.x >> 3, s = blockIdx.x & 7;

  // --- load stationary weights into registers as A-frags ---
  short8 a[6][8];
  {
    const unsigned short* wb = Whh + (long)d*768*256;
    #pragma unroll
    for (int rt = 0; rt < 6; ++rt) {
      #pragma unroll
      for (int kf = 0; kf < 8; ++kf)
        a[rt][kf] = *(const short8*)&wb[(wv*96 + rt*16 + (lane&15))*256 + kf*32 + (lane>>4)*8];
    }
  }

  // --- gate-thread identity: owns h[bcol][j0..j0+8) ---
  const int bcol = tid & 15;
  const int j0 = (tid >> 4) * 8;

  float hr[8];
  {
    const float* hp = h0 + ((long)(layer*2 + d)*BATCH + s*16 + bcol)*HID + j0;
    #pragma unroll
    for (int i = 0; i < 8; ++i) hr[i] = hp[i];
    short8 hb;
    #pragma unroll
    for (int i = 0; i < 8; ++i) hb[i] = (short)f2bf(hr[i]);
    *(short8*)&hT2[tid*8] = hb;
  }
  float bn[8];
  {
    const float* bp = bhh + d*768 + 512 + j0;
    #pragma unroll
    for (int i = 0; i < 8; ++i) bn[i] = bp[i];
  }
  const int mb = s*16 + bcol;

  for (int t = 0; t < 512; ++t) {
    const int tseq = d ? (511 - t) : t;
    const long m = (long)tseq*BATCH + mb;
    const unsigned short* gxp = gx + ((long)d*MROWS + m)*768;
    __syncthreads();   // hT2 ready; ghbuf free for reuse
    // prefetch gate_x (independent of h; hides under MFMA phase)
    short8 xr = *(const short8*)(gxp + j0);
    short8 xz = *(const short8*)(gxp + 256 + j0);
    short8 xn = *(const short8*)(gxp + 512 + j0);

    // --- matvec phase: gh = W_hh * h ---
    f32x4 acc[6];
    #pragma unroll
    for (int rt = 0; rt < 6; ++rt) acc[rt] = (f32x4)0.0f;
    #pragma unroll
    for (int kf = 0; kf < 8; ++kf) {
      short8 b = *(const short8*)&hT2[(kf*64 + lane)*8];
      #pragma unroll
      for (int rt = 0; rt < 6; ++rt)
        acc[rt] = __builtin_amdgcn_mfma_f32_16x16x32_bf16(a[rt][kf], b, acc[rt], 0, 0, 0);
    }
    {
      const int col = lane & 15, gr = (lane >> 4) * 4;
      #pragma unroll
      for (int rt = 0; rt < 6; ++rt)
        *(f32x4*)&ghbuf[col*772 + wv*96 + rt*16 + gr] = acc[rt];
    }
    __syncthreads();   // ghbuf ready

    // --- gate phase ---
    f32x4 gr0 = *(const f32x4*)&ghbuf[bcol*772 + j0];
    f32x4 gr1 = *(const f32x4*)&ghbuf[bcol*772 + j0 + 4];
    f32x4 gz0 = *(const f32x4*)&ghbuf[bcol*772 + 256 + j0];
    f32x4 gz1 = *(const f32x4*)&ghbuf[bcol*772 + 256 + j0 + 4];
    f32x4 gn0 = *(const f32x4*)&ghbuf[bcol*772 + 512 + j0];
    f32x4 gn1 = *(const f32x4*)&ghbuf[bcol*772 + 512 + j0 + 4];
    short8 ho;
    #pragma unroll
    for (int i = 0; i < 8; ++i) {
      const float ghr = (i < 4) ? gr0[i] : gr1[i-4];
      const float ghz = (i < 4) ? gz0[i] : gz1[i-4];
      const float ghn = (i < 4) ? gn0[i] : gn1[i-4];
      const float r = sigm(bf2f((unsigned short)xr[i]) + ghr);
      const float z = sigm(bf2f((unsigned short)xz[i]) + ghz);
      const float nn = tanh_f(bf2f((unsigned short)xn[i]) + r * (ghn + bn[i]));
      hr[i] = (1.0f - z) * nn + z * hr[i];
      ho[i] = (short)f2bf(hr[i]);
    }
    *(short8*)&hT2[tid*8] = ho;                       // next step's B-frags
    *(short8*)(act + m*512 + d*256 + j0) = ho;        // layer output
    if (t == 511) {
      float* op = hOut + ((long)(layer*2 + d)*BATCH + s*16 + bcol)*HID + j0;
      #pragma unroll
      for (int i = 0; i < 8; ++i) op[i] = hr[i];
    }
  }
}

extern "C" void kernel_launch(void* const* d_in, const int* in_sizes, int n_in,
                              void* d_out, int out_size, void* d_ws, size_t ws_size,
                              hipStream_t stream) {
  const float* x   = (const float*)d_in[0];
  const float* h0  = (const float*)d_in[1];
  const float* wih = (const float*)d_in[2];
  const float* whh = (const float*)d_in[3];
  const float* bih = (const float*)d_in[4];
  const float* bhh = (const float*)d_in[5];
  float* out = (float*)d_out;
  char* ws = (char*)d_ws;
  // ws layout
  unsigned short* actA = (unsigned short*)ws;                    //  67,108,864 B
  unsigned short* actB = (unsigned short*)(ws + 67108864);       //  67,108,864 B
  unsigned short* gxb  = (unsigned short*)(ws + 134217728);      // 201,326,592 B
  unsigned short* wihb = (unsigned short*)(ws + 335544320);      //   4,718,592 B
  unsigned short* whhb = (unsigned short*)(ws + 340262912);      //   2,359,296 B
  if (ws_size < 342622208ULL) return;

  hipLaunchKernelGGL(cvt_bf16, dim3(2048), dim3(256), 0, stream, x,   actA, (long)33554432);
  hipLaunchKernelGGL(cvt_bf16, dim3(512),  dim3(256), 0, stream, wih, wihb, (long)2359296);
  hipLaunchKernelGGL(cvt_bf16, dim3(256),  dim3(256), 0, stream, whh, whhb, (long)1179648);

  for (int l = 0; l < 3; ++l) {
    const unsigned short* Ain = (l == 1) ? actB : actA;  // l0:actA(x), l1:actB, l2:actA
    unsigned short* Aout      = (l == 1) ? actA : actB;  // l0->actB, l1->actA, l2->actB
    hipLaunchKernelGGL(gemm_gx, dim3(6144), dim3(256), 0, stream,
                       Ain, wihb + (long)l*1536*512, bih + l*1536, bhh + l*1536, gxb);
    hipLaunchKernelGGL(gru_rec, dim3(16), dim3(512), 0, stream,
                       gxb, whhb + (long)l*2*768*256, bhh + l*1536, h0, Aout, out, l);
  }
}

// Round 2
// 5107.626 us; speedup vs baseline: 1.1159x; 1.1159x over previous
//
#include <hip/hip_runtime.h>
#include <stdint.h>

#define T_LEN 512
#define BATCH 128
#define HID 256
#define MROWS (T_LEN*BATCH)   // 65536
#define KIN 512

typedef __attribute__((ext_vector_type(8))) short short8;
typedef __attribute__((ext_vector_type(4))) float f32x4;
typedef __attribute__((ext_vector_type(4))) unsigned short u16x4;

static __device__ __forceinline__ float bf2f(unsigned short u) {
  union { unsigned int u; float f; } c; c.u = ((unsigned int)u) << 16; return c.f;
}
static __device__ __forceinline__ unsigned short f2bf(float f) {
  union { float f; unsigned int u; } c; c.f = f;
  unsigned int x = c.u;
  x += 0x7fffu + ((x >> 16) & 1u);   // RNE
  return (unsigned short)(x >> 16);
}
static __device__ __forceinline__ void gload_lds16(const void* g, void* l) {
  __builtin_amdgcn_global_load_lds((const __attribute__((address_space(1))) unsigned int*)g,
                                   (__attribute__((address_space(3))) unsigned int*)l,
                                   16, 0, 0);
}
static __device__ __forceinline__ float fast_sigm(float x) {
  return __builtin_amdgcn_rcpf(1.0f + __expf(-x));
}
static __device__ __forceinline__ float fast_tanh(float x) {
  // 1 - 2/(1+e^{2x}); e=inf -> 1, e=0 -> -1
  float e = __expf(2.0f * x);
  return 1.0f - 2.0f * __builtin_amdgcn_rcpf(1.0f + e);
}

// ---------------- fp32 -> bf16 conversion (n % 4 == 0) ----------------
__global__ void cvt_bf16(const float* __restrict__ in, unsigned short* __restrict__ out, long n) {
  long i = ((long)blockIdx.x * blockDim.x + threadIdx.x) * 4;
  const long stride = (long)gridDim.x * blockDim.x * 4;
  for (; i < n; i += stride) {
    f32x4 v = *(const f32x4*)(in + i);
    u16x4 o;
    o[0] = f2bf(v[0]); o[1] = f2bf(v[1]); o[2] = f2bf(v[2]); o[3] = f2bf(v[3]);
    *(u16x4*)(out + i) = o;
  }
}

// ---------------- input GEMM: gate_x = A[65536,512] * W[1536,512]^T + bias ----------------
__global__ __launch_bounds__(256) void gemm_gx(
    const unsigned short* __restrict__ A,
    const unsigned short* __restrict__ Bw,
    const float* __restrict__ bih,
    const float* __restrict__ bhh,
    unsigned short* __restrict__ gx)
{
  __shared__ unsigned short As[128*64];
  __shared__ unsigned short Bs[128*64];
  const int tid = threadIdx.x, lane = tid & 63, wv = tid >> 6;
  const int bid = blockIdx.x;
  const int nt = bid % 12; const long mt = bid / 12;
  const long m0 = mt * 128; const int n0 = nt * 128;
  const int wm = wv >> 1, wn = wv & 1;
  const int r8 = lane >> 3, c8 = lane & 7;

  f32x4 acc[4][4];
  #pragma unroll
  for (int i = 0; i < 4; ++i) {
    #pragma unroll
    for (int j = 0; j < 4; ++j) acc[i][j] = (f32x4)0.0f;
  }

  for (int kt = 0; kt < 8; ++kt) {
    const int kb = kt * 64;
    #pragma unroll
    for (int c = 0; c < 4; ++c) {
      const int rr = c*32 + wv*8;
      gload_lds16(A  + (m0 + rr + r8) * (long)KIN + kb + c8*8, &As[rr*64]);
      gload_lds16(Bw + (long)(n0 + rr + r8) * KIN + kb + c8*8, &Bs[rr*64]);
    }
    __syncthreads();
    #pragma unroll
    for (int kk = 0; kk < 2; ++kk) {
      short8 af[4], bfr[4];
      #pragma unroll
      for (int i = 0; i < 4; ++i)
        af[i] = *(const short8*)&As[(wm*64 + i*16 + (lane&15))*64 + kk*32 + (lane>>4)*8];
      #pragma unroll
      for (int j = 0; j < 4; ++j)
        bfr[j] = *(const short8*)&Bs[(wn*64 + j*16 + (lane&15))*64 + kk*32 + (lane>>4)*8];
      #pragma unroll
      for (int i = 0; i < 4; ++i) {
        #pragma unroll
        for (int j = 0; j < 4; ++j)
          acc[i][j] = __builtin_amdgcn_mfma_f32_16x16x32_bf16(af[i], bfr[j], acc[i][j], 0, 0, 0);
      }
    }
    __syncthreads();
  }

  const int d = (n0 >= 768) ? 1 : 0;
  #pragma unroll
  for (int j = 0; j < 4; ++j) {
    const int n = n0 + wn*64 + j*16 + (lane & 15);
    const int g = n - d*768;
    const float bias = bih[n] + ((g < 512) ? bhh[n] : 0.0f);
    #pragma unroll
    for (int i = 0; i < 4; ++i) {
      const long row = m0 + wm*64 + i*16 + (lane >> 4)*4;
      unsigned short* op = gx + ((long)d*MROWS + row)*768 + g;
      #pragma unroll
      for (int r = 0; r < 4; ++r)
        op[(long)r*768] = f2bf(acc[i][j][r] + bias);
    }
  }
}

// ---------------- recurrent scan: fused gates on MFMA accumulators ----------------
// 16 WGs (dir = blk>>3, batch slice of 16 = blk&7), 512 threads (8 waves).
// Wave v owns the SAME j-window in all 3 gates: rows {v*32..+32} in each 256-block.
// -> MFMA acc holds r/z/n for identical (batch col, j) in the same lane: gate math
//    runs on registers, no LDS exchange. h double-buffered in LDS (linear B-frag
//    layout). ONE raw s_barrier per step, lgkmcnt-only wait; vmcnt never drained
//    in-loop (act stores + gx prefetch float across barriers).
__global__ __launch_bounds__(512) void gru_rec(
    const unsigned short* __restrict__ gx,    // [2][65536][768] bf16
    const unsigned short* __restrict__ Whh,   // [2][768][256] bf16 (this layer)
    const float* __restrict__ bhh,            // [2][768] fp32 (this layer)
    const float* __restrict__ h0,             // [6][128][256]
    unsigned short* __restrict__ act,         // [65536][512] bf16 (layer output)
    float* __restrict__ hOut,                 // d_out [6][128][256]
    const int layer)
{
  __shared__ unsigned short hbuf[2][4096];    // [buf][ (j>>3)*128 + col*8 + (j&7) ]
  const int tid = threadIdx.x, lane = tid & 63, wv = tid >> 6;
  const int d = blockIdx.x >> 3, s = blockIdx.x & 7;
  const int g = lane >> 4, c = lane & 15;
  const int mb = s*16 + c;

  // --- stationary weights: rt = gate*2+q -> rows gate*256 + wv*32 + q*16 ---
  short8 a[6][8];
  {
    const unsigned short* wb = Whh + (long)d*768*256;
    #pragma unroll
    for (int rt = 0; rt < 6; ++rt) {
      const int rowb = (rt >> 1)*256 + wv*32 + (rt & 1)*16;
      #pragma unroll
      for (int kf = 0; kf < 8; ++kf)
        a[rt][kf] = *(const short8*)&wb[(rowb + c)*256 + kf*32 + g*8];
    }
  }

  const int jb0 = wv*32 + g*4;                 // q=0 j-base; q=1 adds +16
  const int woff0 = (wv*4 + (g>>1))*128 + c*8 + (g&1)*4;   // hbuf idx for q=0
  const int woff1 = woff0 + 2*128;                          // q=1 (j+16 -> group+2)

  // --- init h (bf16 regs + LDS buf 0) ---
  u16x4 hq[2];
  {
    const float* hp = h0 + ((long)(layer*2 + d)*BATCH + mb)*HID + jb0;
    #pragma unroll
    for (int q = 0; q < 2; ++q) {
      #pragma unroll
      for (int i = 0; i < 4; ++i) hq[q][i] = f2bf(hp[q*16 + i]);
    }
    *(u16x4*)&hbuf[0][woff0] = hq[0];
    *(u16x4*)&hbuf[0][woff1] = hq[1];
  }
  float bn[2][4];
  {
    const float* bp = bhh + d*768 + 512 + jb0;
    #pragma unroll
    for (int q = 0; q < 2; ++q)
      #pragma unroll
      for (int i = 0; i < 4; ++i) bn[q][i] = bp[q*16 + i];
  }

  // --- running pointers (gx row / act row for this lane) ---
  const long t0 = d ? 511 : 0;
  const long dgx = d ? -(long)(BATCH*768) : (long)(BATCH*768);
  const long dac = d ? -(long)(BATCH*512) : (long)(BATCH*512);
  const unsigned short* pg = gx + ((long)d*MROWS + t0*BATCH + mb)*768 + jb0;
  unsigned short* pa = act + (t0*BATCH + mb)*512 + d*256 + jb0;
  float* po = hOut + ((long)(layer*2 + d)*BATCH + mb)*HID + jb0;

  // --- prefetch gx for t=0 ---
  u16x4 cx[3][2], nx[3][2];
  #pragma unroll
  for (int gt = 0; gt < 3; ++gt) {
    #pragma unroll
    for (int q = 0; q < 2; ++q)
      cx[gt][q] = *(const u16x4*)(pg + gt*256 + q*16);
  }

  asm volatile("s_waitcnt lgkmcnt(0)\n\ts_barrier" ::: "memory");

  int p = 0;
  #pragma unroll 1
  for (int t = 0; t < 512; ++t) {
    // 1. issue gx prefetch for t+1 (consumed next step; never drained by barrier)
    {
      const unsigned short* pn = pg + dgx;
      #pragma unroll
      for (int gt = 0; gt < 3; ++gt) {
        #pragma unroll
        for (int q = 0; q < 2; ++q)
          nx[gt][q] = *(const u16x4*)(pn + gt*256 + q*16);
      }
    }

    // 2. matvec: acc[rt] = W_hh[rows(rt)] * h   (B-frags from LDS, linear layout)
    f32x4 acc[6];
    #pragma unroll
    for (int rt = 0; rt < 6; ++rt) acc[rt] = (f32x4)0.0f;
    {
      const unsigned short* hb = &hbuf[p][0];
      #pragma unroll
      for (int kf = 0; kf < 8; ++kf) {
        short8 b = *(const short8*)&hb[(kf*64 + lane)*8];
        #pragma unroll
        for (int rt = 0; rt < 6; ++rt)
          acc[rt] = __builtin_amdgcn_mfma_f32_16x16x32_bf16(a[rt][kf], b, acc[rt], 0, 0, 0);
      }
    }

    // 3. gates directly on accumulators (r/z/n for same (col,j) live in this lane)
    #pragma unroll
    for (int q = 0; q < 2; ++q) {
      u16x4 hn;
      #pragma unroll
      for (int i = 0; i < 4; ++i) {
        const float r = fast_sigm(bf2f(cx[0][q][i]) + acc[0*2+q][i]);
        const float z = fast_sigm(bf2f(cx[1][q][i]) + acc[1*2+q][i]);
        const float nn = fast_tanh(bf2f(cx[2][q][i]) + r * (acc[2*2+q][i] + bn[q][i]));
        const float hf = nn + z * (bf2f(hq[q][i]) - nn);
        hn[i] = f2bf(hf);
        if (t == 511) po[q*16 + i] = hf;
      }
      hq[q] = hn;
    }

    // 4. publish h_{t+1}: LDS (next buffer) + layer output (store floats away)
    *(u16x4*)&hbuf[p^1][woff0] = hq[0];
    *(u16x4*)&hbuf[p^1][woff1] = hq[1];
    *(u16x4*)(pa)      = hq[0];
    *(u16x4*)(pa + 16) = hq[1];

    // 5. rotate pipeline regs + pointers, one barrier (LDS-only wait)
    #pragma unroll
    for (int gt = 0; gt < 3; ++gt) {
      #pragma unroll
      for (int q = 0; q < 2; ++q) cx[gt][q] = nx[gt][q];
    }
    pg += dgx; pa += dac; p ^= 1;
    asm volatile("s_waitcnt lgkmcnt(0)\n\ts_barrier" ::: "memory");
  }
}

extern "C" void kernel_launch(void* const* d_in, const int* in_sizes, int n_in,
                              void* d_out, int out_size, void* d_ws, size_t ws_size,
                              hipStream_t stream) {
  const float* x   = (const float*)d_in[0];
  const float* h0  = (const float*)d_in[1];
  const float* wih = (const float*)d_in[2];
  const float* whh = (const float*)d_in[3];
  const float* bih = (const float*)d_in[4];
  const float* bhh = (const float*)d_in[5];
  float* out = (float*)d_out;
  char* ws = (char*)d_ws;
  unsigned short* actA = (unsigned short*)ws;                    //  67,108,864 B
  unsigned short* actB = (unsigned short*)(ws + 67108864);       //  67,108,864 B
  unsigned short* gxb  = (unsigned short*)(ws + 134217728);      // 201,326,592 B
  unsigned short* wihb = (unsigned short*)(ws + 335544320);      //   4,718,592 B
  unsigned short* whhb = (unsigned short*)(ws + 340262912);      //   2,359,296 B
  if (ws_size < 342622208ULL) return;

  hipLaunchKernelGGL(cvt_bf16, dim3(2048), dim3(256), 0, stream, x,   actA, (long)33554432);
  hipLaunchKernelGGL(cvt_bf16, dim3(512),  dim3(256), 0, stream, wih, wihb, (long)2359296);
  hipLaunchKernelGGL(cvt_bf16, dim3(256),  dim3(256), 0, stream, whh, whhb, (long)1179648);

  for (int l = 0; l < 3; ++l) {
    const unsigned short* Ain = (l == 1) ? actB : actA;
    unsigned short* Aout      = (l == 1) ? actA : actB;
    hipLaunchKernelGGL(gemm_gx, dim3(6144), dim3(256), 0, stream,
                       Ain, wihb + (long)l*1536*512, bih + l*1536, bhh + l*1536, gxb);
    hipLaunchKernelGGL(gru_rec, dim3(16), dim3(512), 0, stream,
                       gxb, whhb + (long)l*2*768*256, bhh + l*1536, h0, Aout, out, l);
  }
}